// Round 1
// 509.453 us; speedup vs baseline: 1.0015x; 1.0015x over previous
//
#include <hip/hip_runtime.h>
#include <stdint.h>

#define NB 16
#define CC 64
#define HH 256
#define WW 256
#define HP 258
#define WP 258

// ---- pack weights: bit c of word (o,kh,kw) = (w[o][c][kh][kw] < 0) ----
__global__ __launch_bounds__(256) void pack_w_kernel(const float* __restrict__ w,
                                                     uint64_t* __restrict__ pW) {
    int widx = (blockIdx.x * 256 + threadIdx.x) >> 6;  // one packed word per wave
    int lane = threadIdx.x & 63;                       // lane = input channel
    if (widx >= CC * 9) return;
    int o = widx / 9;
    int t = widx % 9;
    float v = w[(size_t)o * (CC * 9) + (size_t)lane * 9 + t];
    unsigned long long m = __ballot(v < 0.0f);
    if (lane == 0) pW[widx] = m;
}

// ---- pack activations + zero the pad ring (side job of blockIdx.x==0) ----
__global__ __launch_bounds__(256) void pack_x_kernel(const float* __restrict__ x,
                                                     uint64_t* __restrict__ pX) {
    int n = blockIdx.y;
    if (blockIdx.x == 0) {  // zero this image's 1028 pad words
        for (int r = threadIdx.x; r < 1028; r += 256) {
            size_t base = (size_t)n * HP * WP;
            size_t off;
            if (r < 258) off = (size_t)r;                          // top pad row
            else if (r < 516) off = (size_t)257 * WP + (r - 258);  // bottom pad row
            else {
                int rr = r - 516;                                  // 0..511 -> side cols
                off = (size_t)(1 + (rr >> 1)) * WP + ((rr & 1) ? 257 : 0);
            }
            pX[base + off] = 0;
        }
    }
    int g = blockIdx.x * 256 + threadIdx.x;  // 4-pixel group within image, 0..16383
    const float4* xv = (const float4*)x;
    uint64_t b0 = 0, b1 = 0, b2 = 0, b3 = 0;
#pragma unroll 16
    for (int c = 0; c < CC; ++c) {
        float4 v = xv[((size_t)(n * CC + c) << 14) + g];  // coalesced: lanes contiguous in w
        b0 |= (uint64_t)(v.x < 0.0f) << c;
        b1 |= (uint64_t)(v.y < 0.0f) << c;
        b2 |= (uint64_t)(v.z < 0.0f) << c;
        b3 |= (uint64_t)(v.w < 0.0f) << c;
    }
    int px = g << 2;
    int h = px >> 8;
    int w = px & 255;
    uint64_t* dst = pX + ((size_t)n * HP + (h + 1)) * WP + (w + 1);
    dst[0] = b0; dst[1] = b1; dst[2] = b2; dst[3] = b3;
}

// ---- binary conv (xnor-popcount) + bias + relu + eval BN ----
// Block = (n, 4-row group). Wave wid -> row h; lane l -> pixel quad 4l..4l+3.
// v2 changes vs. 510us baseline:
//  * sq padded to [CC][10] (80B rows, 16B-aligned) -> 5x ds_read_b128 instead of 9x b64
//  * si/sf merged into int4/float4 LDS arrays (16B-aligned rows) -> 3x b128
//  * top/bottom boundary corrections hoisted behind a block-uniform branch:
//    interior 62/64 hq-groups run an EDGE=false loop with zero hcorr logic
//  * epilogue: per-o A=576+bias precomputed, per-pixel is cvt+fma(-2)+max+fma (4 ops)
template<bool EDGE>
__device__ __forceinline__ void conv_rows(const uint64_t (*__restrict__ sq)[10],
                                          const int4 (*__restrict__ siv)[2],
                                          const float4* __restrict__ sfv,
                                          const uint64_t xw[3][6],
                                          bool isT, bool isB, bool isL, bool isR,
                                          float4* __restrict__ out4, size_t obase) {
#pragma unroll 2
    for (int o = 0; o < CC; ++o) {
        const ulonglong2* qp = (const ulonglong2*)(&sq[o][0]);  // uniform addr: LDS broadcast
        ulonglong2 q01 = qp[0], q23 = qp[1], q45 = qp[2], q67 = qp[3], q8p = qp[4];
        uint64_t q0 = q01.x, q1 = q01.y, q2 = q23.x, q3 = q23.y, q4 = q45.x,
                 q5 = q45.y, q6 = q67.x, q7 = q67.y, q8 = q8p.x;
        float4 ff = sfv[o];  // bias, inv, addc, pad
        int4 e0 = siv[o][0]; // top,bot,left,right
        int cL = e0.z, cR = e0.w;
        float A;
        if (EDGE) {
            int4 e1 = siv[o][1];  // ct0, ct2, ct6, ct8
            int hcorr = 0;
            if (isT) { hcorr += e0.x; cL -= e1.x; cR -= e1.y; }
            if (isB) { hcorr += e0.y; cL -= e1.z; cR -= e1.w; }
            A = (float)(576 - hcorr) + ff.x;
        } else {
            A = 576.0f + ff.x;
        }
        float AL = isL ? A - (float)cL : A;  // only lane 0 differs
        float AR = isR ? A - (float)cR : A;  // only lane 63 differs

        float4 res;
        float* resp = (float*)&res;
#pragma unroll
        for (int j = 0; j < 4; ++j) {
            int p = __popcll(xw[0][j] ^ q0) + __popcll(xw[0][j + 1] ^ q1) + __popcll(xw[0][j + 2] ^ q2)
                  + __popcll(xw[1][j] ^ q3) + __popcll(xw[1][j + 1] ^ q4) + __popcll(xw[1][j + 2] ^ q5)
                  + __popcll(xw[2][j] ^ q6) + __popcll(xw[2][j + 1] ^ q7) + __popcll(xw[2][j + 2] ^ q8);
            float Aj = (j == 0) ? AL : ((j == 3) ? AR : A);  // compile-time select (j unrolled)
            float yf = fmaf((float)p, -2.0f, Aj);            // 576 - 2p - corr + bias
            yf = fmaxf(yf, 0.0f);                            // ReLU
            resp[j] = fmaf(yf, ff.y, ff.z);                  // eval BN
        }
        out4[obase + ((size_t)o << 14)] = res;  // wave store: 1KB contiguous
    }
}

__global__ __launch_bounds__(256, 4) void bconv_kernel(const uint64_t* __restrict__ pX,
                                                       const uint64_t* __restrict__ pW,
                                                       const float* __restrict__ bias,
                                                       const float* __restrict__ gamma,
                                                       const float* __restrict__ beta,
                                                       const float* __restrict__ rmean,
                                                       const float* __restrict__ rvar,
                                                       float* __restrict__ out) {
    __shared__ __align__(16) uint64_t sq[CC][10];  // packed weights, padded row for b128 reads
    __shared__ int4 siv[CC][2];                    // {top,bot,left,right}, {ct0,ct2,ct6,ct8}
    __shared__ float4 sfv[CC];                     // bias, inv, addc, pad

    int tid = threadIdx.x;
    if (tid < CC) {
        int o = tid;
        int ct[9];
#pragma unroll
        for (int t = 0; t < 9; ++t) {
            uint64_t q = pW[o * 9 + t];
            sq[o][t] = q;
            ct[t] = 64 - 2 * __popcll(q);  // pad-tap correction (pad word = 0)
        }
        sq[o][9] = 0;
        siv[o][0] = make_int4(ct[0] + ct[1] + ct[2],   // top
                              ct[6] + ct[7] + ct[8],   // bot
                              ct[0] + ct[3] + ct[6],   // left
                              ct[2] + ct[5] + ct[8]);  // right
        siv[o][1] = make_int4(ct[0], ct[2], ct[6], ct[8]);
        float inv = gamma[o] / sqrtf(rvar[o] + 1e-5f);
        sfv[o] = make_float4(bias[o], inv, beta[o] - rmean[o] * inv, 0.0f);
    }

    int blk = blockIdx.x;  // 0..1023
    int n = blk >> 6;
    int hq = blk & 63;
    int l = tid & 63;      // lane -> pixel quad
    int wid = tid >> 6;    // wave -> row within 4-row group
    int h = hq * 4 + wid;  // output row; padded rows h..h+2

    // X window: 3 padded rows, cols 4l..4l+5 (outputs 4l+j need cols 4l+j..4l+j+2, j<=3)
    uint64_t xw[3][6];
    const uint64_t* rowp = pX + ((size_t)n * HP + h) * WP + 4 * l;
#pragma unroll
    for (int r = 0; r < 3; ++r) {
        const ulonglong2* p2 = (const ulonglong2*)(rowp + (size_t)r * WP);
        ulonglong2 a = p2[0], b = p2[1], c = p2[2];
        xw[r][0] = a.x; xw[r][1] = a.y; xw[r][2] = b.x;
        xw[r][3] = b.y; xw[r][4] = c.x; xw[r][5] = c.y;
    }

    __syncthreads();

    bool isL = (l == 0), isR = (l == 63);
    bool isT = (h == 0), isB = (h == 255);
    float4* out4 = (float4*)out;
    size_t obase = ((size_t)(n * CC) << 14) + (size_t)h * 64 + l;

    if (hq == 0 || hq == 63) {  // block-uniform: scalar branch, no divergence
        conv_rows<true>(sq, siv, sfv, xw, isT, isB, isL, isR, out4, obase);
    } else {
        conv_rows<false>(sq, siv, sfv, xw, false, false, isL, isR, out4, obase);
    }
}

extern "C" void kernel_launch(void* const* d_in, const int* in_sizes, int n_in,
                              void* d_out, int out_size, void* d_ws, size_t ws_size,
                              hipStream_t stream) {
    const float* x     = (const float*)d_in[0];
    const float* w     = (const float*)d_in[1];
    const float* bias  = (const float*)d_in[2];
    const float* gamma = (const float*)d_in[3];
    const float* beta  = (const float*)d_in[4];
    const float* rmean = (const float*)d_in[5];
    const float* rvar  = (const float*)d_in[6];
    float* out = (float*)d_out;

    uint64_t* pX = (uint64_t*)d_ws;
    size_t pXwords = (size_t)NB * HP * WP;  // ~8.5 MiB
    uint64_t* pW = pX + pXwords;            // 576 words

    pack_w_kernel<<<(CC * 9 + 3) / 4, 256, 0, stream>>>(w, pW);
    pack_x_kernel<<<dim3(64, NB), 256, 0, stream>>>(x, pX);
    bconv_kernel<<<NB * 64, 256, 0, stream>>>(pX, pW, bias, gamma, beta, rmean, rvar, out);
}